// Round 1
// baseline (1538.124 us; speedup 1.0000x reference)
//
#include <hip/hip_runtime.h>
#include <math.h>

#define NB 8
#define C 256
#define HW 1024
#define NS 64

// ---------------- block reduction helper (256 threads = 4 waves) ----------------
__device__ __forceinline__ float blockReduceSum(float v, float* s4) {
    #pragma unroll
    for (int o = 32; o; o >>= 1) v += __shfl_down(v, o);
    __syncthreads();                       // protect s4 reuse across calls
    if ((threadIdx.x & 63) == 0) s4[threadIdx.x >> 6] = v;
    __syncthreads();
    return s4[0] + s4[1] + s4[2] + s4[3];
}

// ---------------- K1: seg_s = ws1 . seg + bs1 ; seg_c = ws11 . seg + bs11 ----------------
// grid (NS, NB), block 256. Each block: one (n,s) row of both outputs.
__global__ void k_conv_sc(const float* __restrict__ seg,
                          const float* __restrict__ ws1, const float* __restrict__ bs1,
                          const float* __restrict__ ws11, const float* __restrict__ bs11,
                          float* __restrict__ seg_s, float* __restrict__ seg_c) {
    int s = blockIdx.x, n = blockIdx.y, tid = threadIdx.x;
    __shared__ float w1[C], w2[C];
    w1[tid] = ws1[s * C + tid];
    w2[tid] = ws11[s * C + tid];
    __syncthreads();
    const float* sb = seg + (size_t)n * C * HW;
    float a0 = 0, a1 = 0, a2 = 0, a3 = 0, b0 = 0, b1 = 0, b2 = 0, b3 = 0;
    for (int c = 0; c < C; ++c) {
        const float* row = sb + (size_t)c * HW;
        float w1c = w1[c], w2c = w2[c];
        float s0 = row[tid], s1 = row[tid + 256], s2 = row[tid + 512], s3 = row[tid + 768];
        a0 += s0 * w1c; a1 += s1 * w1c; a2 += s2 * w1c; a3 += s3 * w1c;
        b0 += s0 * w2c; b1 += s1 * w2c; b2 += s2 * w2c; b3 += s3 * w2c;
    }
    float bias1 = bs1[s], bias2 = bs11[s];
    float* o1 = seg_s + ((size_t)n * NS + s) * HW;
    float* o2 = seg_c + ((size_t)n * NS + s) * HW;
    o1[tid] = a0 + bias1; o1[tid + 256] = a1 + bias1; o1[tid + 512] = a2 + bias1; o1[tid + 768] = a3 + bias1;
    o2[tid] = b0 + bias2; o2[tid + 256] = b1 + bias2; o2[tid + 512] = b2 + bias2; o2[tid + 768] = b3 + bias2;
}

// ---------------- K2: pooled[n,c] = mean_hw seg ----------------
__global__ void k_pooled(const float* __restrict__ seg, float* __restrict__ pooled) {
    int c = blockIdx.x, n = blockIdx.y, tid = threadIdx.x;
    const float* row = seg + ((size_t)n * C + c) * HW;
    float acc = row[tid] + row[tid + 256] + row[tid + 512] + row[tid + 768];
    __shared__ float s4[4];
    float r = blockReduceSum(acc, s4);
    if (tid == 0) pooled[n * C + c] = r * (1.0f / HW);
}

// ---------------- K2b: ca[n,s] = relu(pooled . wmlp^T + bmlp) ----------------
__global__ void k_ca(const float* __restrict__ pooled, const float* __restrict__ wmlp,
                     const float* __restrict__ bmlp, float* __restrict__ ca) {
    int n = blockIdx.x, s = threadIdx.x;  // 64 threads
    __shared__ float pl[C];
    for (int i = s; i < C; i += 64) pl[i] = pooled[n * C + i];
    __syncthreads();
    float acc = 0.f;
    for (int c = 0; c < C; ++c) acc += pl[c] * wmlp[s * C + c];
    float r = acc + bmlp[s];
    ca[n * NS + s] = r > 0.f ? r : 0.f;
}

// ---------------- K3: u, v, seg_ss, edge_mm ----------------
// grid (4, NB, 4roles), block 256
__global__ void k_vecs(const float* __restrict__ seg, const float* __restrict__ edge,
                       const float* __restrict__ seg_s, const float* __restrict__ ca,
                       const float* __restrict__ ws2, const float* __restrict__ bs2,
                       const float* __restrict__ ws3, const float* __restrict__ bs3,
                       float* __restrict__ u, float* __restrict__ vv,
                       float* __restrict__ segss, float* __restrict__ edgemm) {
    int pos = blockIdx.x * 256 + threadIdx.x;
    int n = blockIdx.y, role = blockIdx.z;
    if (role == 0) {  // u[p] = dot64(seg_s_flat + p*64, ca)  (raw view)
        __shared__ float cs[NS];
        if (threadIdx.x < NS) cs[threadIdx.x] = ca[n * NS + threadIdx.x];
        __syncthreads();
        const float* base = seg_s + (size_t)n * NS * HW + (size_t)pos * NS;
        float acc = 0.f;
        #pragma unroll
        for (int s = 0; s < NS; ++s) acc += base[s] * cs[s];
        u[n * HW + pos] = acc;
    } else if (role == 1) {  // v[q] = sum_s ca[s]*seg_s[s,q]
        __shared__ float cs[NS];
        if (threadIdx.x < NS) cs[threadIdx.x] = ca[n * NS + threadIdx.x];
        __syncthreads();
        const float* base = seg_s + (size_t)n * NS * HW + pos;
        float acc = 0.f;
        #pragma unroll
        for (int s = 0; s < NS; ++s) acc += cs[s] * base[(size_t)s * HW];
        vv[n * HW + pos] = acc;
    } else if (role == 2) {  // seg_ss[q] = ws2*max_c seg + bs2
        const float* base = seg + (size_t)n * C * HW + pos;
        float m = -3.402823466e38f;
        for (int c = 0; c < C; ++c) m = fmaxf(m, base[(size_t)c * HW]);
        segss[n * HW + pos] = ws2[0] * m + bs2[0];
    } else {  // edge_mm[p] = ws3*max_c(seg*edge) + bs3
        const float* sb = seg + (size_t)n * C * HW + pos;
        const float* eb = edge + (size_t)n * C * HW + pos;
        float m = -3.402823466e38f;
        for (int c = 0; c < C; ++c) m = fmaxf(m, sb[(size_t)c * HW] * eb[(size_t)c * HW]);
        edgemm[n * HW + pos] = ws3[0] * m + bs3[0];
    }
}

// ---------------- generic 64x64-tile f32 GEMM, K-step 32 ----------------
// MODE 0: C = acc
// MODE 1: C = acc * e1[n][m] * e2[n][q]           (B-build scaling)
// MODE 2: C = relu(acc + e1[m]) + e2[n][m*ldc+q]  (GCN epilogue)
// MODE 3: C = 0.5*acc + 0.5*e2[n][m*ldc+q]        (APPNP prop)
template <int MODE>
__global__ void k_gemm64(const float* __restrict__ A, long long strideA, int lda,
                         const float* __restrict__ Bm, long long strideB, int ldb,
                         float* __restrict__ Cm, long long strideC, int ldc, int K,
                         const float* __restrict__ e1, long long se1,
                         const float* __restrict__ e2, long long se2) {
    int n = blockIdx.z;
    int m0 = blockIdx.y * 64, q0 = blockIdx.x * 64;
    const float* Ab = A + (size_t)n * strideA;
    const float* Bb = Bm + (size_t)n * strideB;
    float* Cb = Cm + (size_t)n * strideC;
    __shared__ float As[64][33];
    __shared__ float Bs[32][64];
    int tid = threadIdx.x, tx = tid & 15, ty = tid >> 4;
    float acc[4][4] = {};
    for (int k0 = 0; k0 < K; k0 += 32) {
        #pragma unroll
        for (int i = 0; i < 8; ++i) {
            int e = tid + i * 256;
            int ml = e >> 5, kl = e & 31;
            As[ml][kl] = Ab[(size_t)(m0 + ml) * lda + k0 + kl];
        }
        #pragma unroll
        for (int i = 0; i < 8; ++i) {
            int e = tid + i * 256;
            int kl = e >> 6, nl = e & 63;
            Bs[kl][nl] = Bb[(size_t)(k0 + kl) * ldb + q0 + nl];
        }
        __syncthreads();
        #pragma unroll
        for (int kk = 0; kk < 32; ++kk) {
            float a0 = As[ty * 4 + 0][kk], a1 = As[ty * 4 + 1][kk];
            float a2 = As[ty * 4 + 2][kk], a3 = As[ty * 4 + 3][kk];
            float4 b = *(const float4*)&Bs[kk][tx * 4];
            acc[0][0] += a0 * b.x; acc[0][1] += a0 * b.y; acc[0][2] += a0 * b.z; acc[0][3] += a0 * b.w;
            acc[1][0] += a1 * b.x; acc[1][1] += a1 * b.y; acc[1][2] += a1 * b.z; acc[1][3] += a1 * b.w;
            acc[2][0] += a2 * b.x; acc[2][1] += a2 * b.y; acc[2][2] += a2 * b.z; acc[2][3] += a2 * b.w;
            acc[3][0] += a3 * b.x; acc[3][1] += a3 * b.y; acc[3][2] += a3 * b.z; acc[3][3] += a3 * b.w;
        }
        __syncthreads();
    }
    #pragma unroll
    for (int i = 0; i < 4; ++i) {
        int m = m0 + ty * 4 + i;
        float* crow = Cb + (size_t)m * ldc + q0 + tx * 4;
        #pragma unroll
        for (int j = 0; j < 4; ++j) {
            int q = q0 + tx * 4 + j;
            float val = acc[i][j];
            if (MODE == 1) {
                val *= e1[(size_t)n * se1 + m] * e2[(size_t)n * se2 + q];
            } else if (MODE == 2) {
                val = fmaxf(val + e1[m], 0.f) + e2[(size_t)n * se2 + (size_t)m * ldc + q];
            } else if (MODE == 3) {
                val = 0.5f * val + 0.5f * e2[(size_t)n * se2 + (size_t)m * ldc + q];
            }
            crow[j] = val;
        }
    }
}

// ---------------- K5: in-place threshold + symmetrize B ----------------
// block (p,n): handles (p,q) & (q,p) for q>=p -> unique writer per element
__global__ void k_symB(float* __restrict__ B) {
    int p = blockIdx.x, n = blockIdx.y;
    float* Bb = B + (size_t)n * HW * HW;
    for (int q = p + threadIdx.x; q < HW; q += 256) {
        float x = Bb[(size_t)p * HW + q];
        float y = Bb[(size_t)q * HW + p];
        x = x < 0.15f ? 0.f : x;
        y = y < 0.15f ? 0.f : y;
        float m = 0.5f * (x + y);
        Bb[(size_t)p * HW + q] = m;
        Bb[(size_t)q * HW + p] = m;
    }
}

// ---------------- K6: rowsums for sim_c (from u,v) and sim_s (from Bsym) ----------------
__global__ void k_rowsum_cs(const float* __restrict__ B, const float* __restrict__ u,
                            const float* __restrict__ vv, float* __restrict__ dcinv,
                            float* __restrict__ dsinv) {
    int p = blockIdx.x, n = blockIdx.y, tid = threadIdx.x;
    const float* Bb = B + (size_t)n * HW * HW + (size_t)p * HW;
    const float* un = u + n * HW;
    const float* vn = vv + n * HW;
    float up = un[p], vp = vn[p];
    float acc_s = 0.f, acc_c = 0.f;
    for (int q = tid; q < HW; q += 256) {
        acc_s += Bb[q];
        float x = up * vn[q]; x = x < 0.15f ? 0.f : x;
        float y = un[q] * vp; y = y < 0.15f ? 0.f : y;
        acc_c += 0.5f * (x + y);
    }
    __shared__ float s4[4];
    acc_s = blockReduceSum(acc_s, s4);
    acc_c = blockReduceSum(acc_c, s4);
    if (tid == 0) {
        dsinv[n * HW + p] = 1.0f / sqrtf(acc_s + 1.0f);
        dcinv[n * HW + p] = 1.0f / sqrtf(acc_c + 1.0f);
    }
}

// ---------------- K7: sim_pre = sim_c + sim_s (in place over Bsym), rowsum -> dfinv ----------------
__global__ void k_build_sim(float* __restrict__ B, const float* __restrict__ u,
                            const float* __restrict__ vv, const float* __restrict__ dcinv,
                            const float* __restrict__ dsinv, float* __restrict__ dfinv) {
    int p = blockIdx.x, n = blockIdx.y, tid = threadIdx.x;
    float* Bb = B + (size_t)n * HW * HW + (size_t)p * HW;
    const float* un = u + n * HW;
    const float* vn = vv + n * HW;
    const float* dci = dcinv + n * HW;
    const float* dsi = dsinv + n * HW;
    float up = un[p], vp = vn[p], dcp = dci[p], dsp = dsi[p];
    float acc = 0.f;
    for (int q = tid; q < HW; q += 256) {
        float x = up * vn[q]; x = x < 0.15f ? 0.f : x;
        float y = un[q] * vp; y = y < 0.15f ? 0.f : y;
        float delta = (q == p) ? 1.0f : 0.0f;
        float val = (0.5f * (x + y) + delta) * dcp * dci[q] + (Bb[q] + delta) * dsp * dsi[q];
        Bb[q] = val;
        acc += val;
    }
    __shared__ float s4[4];
    acc = blockReduceSum(acc, s4);
    if (tid == 0) dfinv[n * HW + p] = 1.0f / sqrtf(acc + 1.0f);
}

// ---------------- K8: sim = (sim_pre + I)*dfinv_p*dfinv_q ; ACCUM (= or +=) sim ----------------
__global__ void k_norm_accum(float* __restrict__ B, const float* __restrict__ dfinv,
                             float* __restrict__ ACC, int first) {
    int p = blockIdx.x, n = blockIdx.y, tid = threadIdx.x;
    float* Bb = B + (size_t)n * HW * HW + (size_t)p * HW;
    float* Ab = ACC + (size_t)n * HW * HW + (size_t)p * HW;
    const float* df = dfinv + n * HW;
    float dfp = df[p];
    for (int q = tid; q < HW; q += 256) {
        float val = (Bb[q] + ((q == p) ? 1.f : 0.f)) * dfp * df[q];
        Bb[q] = val;
        Ab[q] = first ? val : (Ab[q] + val);
    }
}

// ---------------- K11: final rowsum of mean adjacency ----------------
__global__ void k_final_rowsum(const float* __restrict__ ACC, float* __restrict__ dinv) {
    int p = blockIdx.x, n = blockIdx.y, tid = threadIdx.x;
    const float* Ab = ACC + (size_t)n * HW * HW + (size_t)p * HW;
    float acc = 0.f;
    for (int q = tid; q < HW; q += 256) acc += Ab[q];
    __shared__ float s4[4];
    acc = blockReduceSum(acc, s4);
    if (tid == 0) dinv[n * HW + p] = 1.0f / sqrtf(acc * (1.0f / 3.0f) + 1.0f);
}

// ---------------- K12: final normalize (in place) + trace/sumsq/rowsum stats ----------------
__global__ void k_final_norm(float* __restrict__ ACC, const float* __restrict__ dinv,
                             float* __restrict__ rowsf, float* __restrict__ scal) {
    int p = blockIdx.x, n = blockIdx.y, tid = threadIdx.x;
    float* Ab = ACC + (size_t)n * HW * HW + (size_t)p * HW;
    const float* di = dinv + n * HW;
    float dp = di[p];
    float accr = 0.f, accsq = 0.f;
    for (int q = tid; q < HW; q += 256) {
        float val = (Ab[q] * (1.0f / 3.0f) + ((q == p) ? 1.f : 0.f)) * dp * di[q];
        Ab[q] = val;
        accr += val;
        accsq += val * val;
        if (q == p) atomicAdd(&scal[0], val);  // trace (dirichlet)
    }
    __shared__ float s4[4];
    accr = blockReduceSum(accr, s4);
    accsq = blockReduceSum(accsq, s4);
    if (tid == 0) {
        rowsf[n * HW + p] = accr;
        atomicAdd(&scal[1], accsq);
    }
}

// ---------------- K13: regularizer ----------------
__global__ void k_reg(const float* __restrict__ rowsf, const float* __restrict__ scal,
                      float* __restrict__ outreg) {
    int n = blockIdx.x, tid = threadIdx.x;
    float acc = 0.f;
    for (int p = tid; p < HW; p += 256) acc += logf(rowsf[n * HW + p]);
    __shared__ float s4[4];
    acc = blockReduceSum(acc, s4);
    if (tid == 0) {
        float f = -0.1f * acc / 1024.0f + 0.1f * sqrtf(scal[1]) / 1048576.0f;
        outreg[n] = 0.1f * scal[0] + f;
    }
}

// ---------------- K14: APPNP t = relu(relu(x wa1^T + ba1) wa2^T + ba2) ----------------
// block per (p,n), 256 threads; x row = 256 consecutive floats (raw view)
__global__ void k_appnp_t(const float* __restrict__ ori, const float* __restrict__ wa1,
                          const float* __restrict__ ba1, const float* __restrict__ wa2,
                          const float* __restrict__ ba2, float* __restrict__ T) {
    int p = blockIdx.x, n = blockIdx.y, tid = threadIdx.x;
    const float* x = ori + (size_t)n * C * HW + (size_t)p * C;
    float xv = x[tid];
    __shared__ float s4[4];
    __shared__ float h[3];
    float d0 = blockReduceSum(xv * wa1[0 * C + tid], s4);
    float d1 = blockReduceSum(xv * wa1[1 * C + tid], s4);
    float d2 = blockReduceSum(xv * wa1[2 * C + tid], s4);
    if (tid == 0) {
        h[0] = fmaxf(d0 + ba1[0], 0.f);
        h[1] = fmaxf(d1 + ba1[1], 0.f);
        h[2] = fmaxf(d2 + ba1[2], 0.f);
    }
    __syncthreads();
    float t = h[0] * wa2[tid * 3 + 0] + h[1] * wa2[tid * 3 + 1] + h[2] * wa2[tid * 3 + 2] + ba2[tid];
    T[(size_t)n * HW * C + (size_t)p * C + tid] = fmaxf(t, 0.f);
}

// =====================================================================================
extern "C" void kernel_launch(void* const* d_in, const int* in_sizes, int n_in,
                              void* d_out, int out_size, void* d_ws, size_t ws_size,
                              hipStream_t stream) {
    const float* seg_in = (const float*)d_in[0];
    const float* edge   = (const float*)d_in[1];
    const float* ws1    = (const float*)d_in[2];
    const float* bs1    = (const float*)d_in[3];
    const float* ws11   = (const float*)d_in[4];
    const float* bs11   = (const float*)d_in[5];
    const float* ws2    = (const float*)d_in[6];
    const float* bs2    = (const float*)d_in[7];
    const float* ws3    = (const float*)d_in[8];
    const float* bs3    = (const float*)d_in[9];
    const float* wmlp   = (const float*)d_in[10];
    const float* bmlp   = (const float*)d_in[11];
    const float* wgcn   = (const float*)d_in[12];
    const float* bgcn   = (const float*)d_in[13];
    const float* wa1    = (const float*)d_in[14];
    const float* ba1    = (const float*)d_in[15];
    const float* wa2    = (const float*)d_in[16];
    const float* ba2    = (const float*)d_in[17];

    float* out = (float*)d_out;
    float* w = (float*)d_ws;
    float* SEG_A   = w; w += (size_t)NB * C * HW;    // 2M
    float* SEG_SIM = w; w += (size_t)NB * C * HW;    // 2M
    float* SEGS    = w; w += (size_t)NB * NS * HW;   // 512K
    float* SEGC    = w; w += (size_t)NB * NS * HW;   // 512K
    float* TBUF    = w; w += (size_t)NB * HW * C;    // 2M
    float* OBUF    = w; w += (size_t)NB * HW * C;    // 2M
    float* BBUF    = w; w += (size_t)NB * HW * HW;   // 8M
    float* ACCUM   = w; w += (size_t)NB * HW * HW;   // 8M
    float* ubuf    = w; w += NB * HW;
    float* vbuf    = w; w += NB * HW;
    float* ssbuf   = w; w += NB * HW;
    float* embuf   = w; w += NB * HW;
    float* dcinv   = w; w += NB * HW;
    float* dsinv   = w; w += NB * HW;
    float* dfinv   = w; w += NB * HW;
    float* rowsf   = w; w += NB * HW;
    float* pooled  = w; w += NB * C;
    float* cabuf   = w; w += NB * NS;
    float* scal    = w; w += 16;

    hipMemsetAsync(scal, 0, 16 * sizeof(float), stream);

    const long long sAdj = (long long)HW * HW;
    const long long sSeg = (long long)C * HW;
    const long long sSgs = (long long)NS * HW;

    for (int it = 0; it < 3; ++it) {
        const float* seg_src = (it == 0) ? seg_in : SEG_A;
        k_conv_sc<<<dim3(NS, NB), 256, 0, stream>>>(seg_src, ws1, bs1, ws11, bs11, SEGS, SEGC);
        k_pooled<<<dim3(C, NB), 256, 0, stream>>>(seg_src, pooled);
        k_ca<<<dim3(NB), 64, 0, stream>>>(pooled, wmlp, bmlp, cabuf);
        k_vecs<<<dim3(4, NB, 4), 256, 0, stream>>>(seg_src, edge, SEGS, cabuf,
                                                   ws2, bs2, ws3, bs3,
                                                   ubuf, vbuf, ssbuf, embuf);
        // B[p,q] = (sigma_T @ sigma) * em[p] * ss[q]   (A = raw view of seg_c, lda=64, K=64)
        k_gemm64<1><<<dim3(16, 16, NB), 256, 0, stream>>>(SEGC, sSgs, NS, SEGC, sSgs, HW,
                                                          BBUF, sAdj, HW, NS,
                                                          embuf, HW, ssbuf, HW);
        k_symB<<<dim3(HW, NB), 256, 0, stream>>>(BBUF);
        k_rowsum_cs<<<dim3(HW, NB), 256, 0, stream>>>(BBUF, ubuf, vbuf, dcinv, dsinv);
        k_build_sim<<<dim3(HW, NB), 256, 0, stream>>>(BBUF, ubuf, vbuf, dcinv, dsinv, dfinv);
        k_norm_accum<<<dim3(HW, NB), 256, 0, stream>>>(BBUF, dfinv, ACCUM, it == 0 ? 1 : 0);
        // seg_sim = seg2 @ sim   (M=256, N=1024, K=1024)
        k_gemm64<0><<<dim3(16, 4, NB), 256, 0, stream>>>(seg_src, sSeg, HW, BBUF, sAdj, HW,
                                                         SEG_SIM, sSeg, HW, HW,
                                                         nullptr, 0, nullptr, 0);
        // seg_new = relu(wgcn @ seg_sim + bgcn) + seg2  (M=256, N=1024, K=256)
        k_gemm64<2><<<dim3(16, 4, NB), 256, 0, stream>>>(wgcn, 0, C, SEG_SIM, sSeg, HW,
                                                         SEG_A, sSeg, HW, C,
                                                         bgcn, 0, seg_src, sSeg);
    }

    // final adjacency: mean of 3 sims -> adj_process(., 0)
    k_final_rowsum<<<dim3(HW, NB), 256, 0, stream>>>(ACCUM, dcinv);
    k_final_norm<<<dim3(HW, NB), 256, 0, stream>>>(ACCUM, dcinv, rowsf, scal);
    k_reg<<<dim3(NB), 256, 0, stream>>>(rowsf, scal, out + (size_t)NB * C * HW);

    // APPNP
    k_appnp_t<<<dim3(HW, NB), 256, 0, stream>>>(seg_in, wa1, ba1, wa2, ba2, TBUF);
    // prop 1: T -> out ; prop 2: out -> OBUF ; prop 3: OBUF -> out
    k_gemm64<3><<<dim3(4, 16, NB), 256, 0, stream>>>(ACCUM, sAdj, HW, TBUF, (long long)HW * C, C,
                                                     out, (long long)HW * C, C, HW,
                                                     nullptr, 0, TBUF, (long long)HW * C);
    k_gemm64<3><<<dim3(4, 16, NB), 256, 0, stream>>>(ACCUM, sAdj, HW, out, (long long)HW * C, C,
                                                     OBUF, (long long)HW * C, C, HW,
                                                     nullptr, 0, TBUF, (long long)HW * C);
    k_gemm64<3><<<dim3(4, 16, NB), 256, 0, stream>>>(ACCUM, sAdj, HW, OBUF, (long long)HW * C, C,
                                                     out, (long long)HW * C, C, HW,
                                                     nullptr, 0, TBUF, (long long)HW * C);
}

// Round 5
// 1340.580 us; speedup vs baseline: 1.1474x; 1.1474x over previous
//
#include <hip/hip_runtime.h>
#include <math.h>

#define NB 8
#define C 256
#define HW 1024
#define NS 64

// ---------------- block reduction helper (256 threads = 4 waves) ----------------
__device__ __forceinline__ float blockReduceSum(float v, float* s4) {
    #pragma unroll
    for (int o = 32; o; o >>= 1) v += __shfl_down(v, o);
    __syncthreads();                       // protect s4 reuse across calls
    if ((threadIdx.x & 63) == 0) s4[threadIdx.x >> 6] = v;
    __syncthreads();
    return s4[0] + s4[1] + s4[2] + s4[3];
}

// ---------------- K1: seg_s = ws1 . seg + bs1 ; seg_c = ws11 . seg + bs11 ----------------
__global__ void k_conv_sc(const float* __restrict__ seg,
                          const float* __restrict__ ws1, const float* __restrict__ bs1,
                          const float* __restrict__ ws11, const float* __restrict__ bs11,
                          float* __restrict__ seg_s, float* __restrict__ seg_c) {
    int s = blockIdx.x, n = blockIdx.y, tid = threadIdx.x;
    __shared__ float w1[C], w2[C];
    w1[tid] = ws1[s * C + tid];
    w2[tid] = ws11[s * C + tid];
    __syncthreads();
    const float* sb = seg + (size_t)n * C * HW;
    float a0 = 0, a1 = 0, a2 = 0, a3 = 0, b0 = 0, b1 = 0, b2 = 0, b3 = 0;
    for (int c = 0; c < C; ++c) {
        const float* row = sb + (size_t)c * HW;
        float w1c = w1[c], w2c = w2[c];
        float s0 = row[tid], s1 = row[tid + 256], s2 = row[tid + 512], s3 = row[tid + 768];
        a0 += s0 * w1c; a1 += s1 * w1c; a2 += s2 * w1c; a3 += s3 * w1c;
        b0 += s0 * w2c; b1 += s1 * w2c; b2 += s2 * w2c; b3 += s3 * w2c;
    }
    float bias1 = bs1[s], bias2 = bs11[s];
    float* o1 = seg_s + ((size_t)n * NS + s) * HW;
    float* o2 = seg_c + ((size_t)n * NS + s) * HW;
    o1[tid] = a0 + bias1; o1[tid + 256] = a1 + bias1; o1[tid + 512] = a2 + bias1; o1[tid + 768] = a3 + bias1;
    o2[tid] = b0 + bias2; o2[tid + 256] = b1 + bias2; o2[tid + 512] = b2 + bias2; o2[tid + 768] = b3 + bias2;
}

// ---------------- K2: pooled[n,c] = mean_hw seg ----------------
__global__ void k_pooled(const float* __restrict__ seg, float* __restrict__ pooled) {
    int c = blockIdx.x, n = blockIdx.y, tid = threadIdx.x;
    const float* row = seg + ((size_t)n * C + c) * HW;
    float acc = row[tid] + row[tid + 256] + row[tid + 512] + row[tid + 768];
    __shared__ float s4[4];
    float r = blockReduceSum(acc, s4);
    if (tid == 0) pooled[n * C + c] = r * (1.0f / HW);
}

// ---------------- K2b: ca[n,s] = relu(pooled . wmlp^T + bmlp) ----------------
__global__ void k_ca(const float* __restrict__ pooled, const float* __restrict__ wmlp,
                     const float* __restrict__ bmlp, float* __restrict__ ca) {
    int n = blockIdx.x, s = threadIdx.x;  // 64 threads
    __shared__ float pl[C];
    for (int i = s; i < C; i += 64) pl[i] = pooled[n * C + i];
    __syncthreads();
    float acc = 0.f;
    for (int c = 0; c < C; ++c) acc += pl[c] * wmlp[s * C + c];
    float r = acc + bmlp[s];
    ca[n * NS + s] = r > 0.f ? r : 0.f;
}

// ---------------- K3: u, v, seg_ss, edge_mm ----------------
__global__ void k_vecs(const float* __restrict__ seg, const float* __restrict__ edge,
                       const float* __restrict__ seg_s, const float* __restrict__ ca,
                       const float* __restrict__ ws2, const float* __restrict__ bs2,
                       const float* __restrict__ ws3, const float* __restrict__ bs3,
                       float* __restrict__ u, float* __restrict__ vv,
                       float* __restrict__ segss, float* __restrict__ edgemm) {
    int pos = blockIdx.x * 256 + threadIdx.x;
    int n = blockIdx.y, role = blockIdx.z;
    if (role == 0) {
        __shared__ float cs[NS];
        if (threadIdx.x < NS) cs[threadIdx.x] = ca[n * NS + threadIdx.x];
        __syncthreads();
        const float* base = seg_s + (size_t)n * NS * HW + (size_t)pos * NS;
        float acc = 0.f;
        #pragma unroll
        for (int s = 0; s < NS; ++s) acc += base[s] * cs[s];
        u[n * HW + pos] = acc;
    } else if (role == 1) {
        __shared__ float cs[NS];
        if (threadIdx.x < NS) cs[threadIdx.x] = ca[n * NS + threadIdx.x];
        __syncthreads();
        const float* base = seg_s + (size_t)n * NS * HW + pos;
        float acc = 0.f;
        #pragma unroll
        for (int s = 0; s < NS; ++s) acc += cs[s] * base[(size_t)s * HW];
        vv[n * HW + pos] = acc;
    } else if (role == 2) {
        const float* base = seg + (size_t)n * C * HW + pos;
        float m = -3.402823466e38f;
        for (int c = 0; c < C; ++c) m = fmaxf(m, base[(size_t)c * HW]);
        segss[n * HW + pos] = ws2[0] * m + bs2[0];
    } else {
        const float* sb = seg + (size_t)n * C * HW + pos;
        const float* eb = edge + (size_t)n * C * HW + pos;
        float m = -3.402823466e38f;
        for (int c = 0; c < C; ++c) m = fmaxf(m, sb[(size_t)c * HW] * eb[(size_t)c * HW]);
        edgemm[n * HW + pos] = ws3[0] * m + bs3[0];
    }
}

// ---------------- generic 64x64-tile f32 GEMM, K-step 32 ----------------
// MODE 0: C = acc
// MODE 1: C = acc * e1[n][m] * e2[n][q]           (B-build scaling)
// MODE 2: C = relu(acc + e1[m]) + e2[n][m*ldc+q]  (GCN epilogue)
// MODE 3: C = 0.5*acc + 0.5*e2[n][m*ldc+q]        (APPNP prop)
template <int MODE>
__global__ void k_gemm64(const float* __restrict__ A, long long strideA, int lda,
                         const float* __restrict__ Bm, long long strideB, int ldb,
                         float* __restrict__ Cm, long long strideC, int ldc, int K,
                         const float* __restrict__ e1, long long se1,
                         const float* __restrict__ e2, long long se2) {
    int n = blockIdx.z;
    int m0 = blockIdx.y * 64, q0 = blockIdx.x * 64;
    const float* Ab = A + (size_t)n * strideA;
    const float* Bb = Bm + (size_t)n * strideB;
    float* Cb = Cm + (size_t)n * strideC;
    __shared__ float As[64][33];
    __shared__ float Bs[32][64];
    int tid = threadIdx.x, tx = tid & 15, ty = tid >> 4;
    float acc[4][4] = {};
    for (int k0 = 0; k0 < K; k0 += 32) {
        #pragma unroll
        for (int i = 0; i < 8; ++i) {
            int e = tid + i * 256;
            int ml = e >> 5, kl = e & 31;
            As[ml][kl] = Ab[(size_t)(m0 + ml) * lda + k0 + kl];
        }
        #pragma unroll
        for (int i = 0; i < 8; ++i) {
            int e = tid + i * 256;
            int kl = e >> 6, nl = e & 63;
            Bs[kl][nl] = Bb[(size_t)(k0 + kl) * ldb + q0 + nl];
        }
        __syncthreads();
        #pragma unroll
        for (int kk = 0; kk < 32; ++kk) {
            float a0 = As[ty * 4 + 0][kk], a1 = As[ty * 4 + 1][kk];
            float a2 = As[ty * 4 + 2][kk], a3 = As[ty * 4 + 3][kk];
            float4 b = *(const float4*)&Bs[kk][tx * 4];
            acc[0][0] += a0 * b.x; acc[0][1] += a0 * b.y; acc[0][2] += a0 * b.z; acc[0][3] += a0 * b.w;
            acc[1][0] += a1 * b.x; acc[1][1] += a1 * b.y; acc[1][2] += a1 * b.z; acc[1][3] += a1 * b.w;
            acc[2][0] += a2 * b.x; acc[2][1] += a2 * b.y; acc[2][2] += a2 * b.z; acc[2][3] += a2 * b.w;
            acc[3][0] += a3 * b.x; acc[3][1] += a3 * b.y; acc[3][2] += a3 * b.z; acc[3][3] += a3 * b.w;
        }
        __syncthreads();
    }
    #pragma unroll
    for (int i = 0; i < 4; ++i) {
        int m = m0 + ty * 4 + i;
        float* crow = Cb + (size_t)m * ldc + q0 + tx * 4;
        #pragma unroll
        for (int j = 0; j < 4; ++j) {
            int q = q0 + tx * 4 + j;
            float val = acc[i][j];
            if (MODE == 1) {
                val *= e1[(size_t)n * se1 + m] * e2[(size_t)n * se2 + q];
            } else if (MODE == 2) {
                val = fmaxf(val + e1[m], 0.f) + e2[(size_t)n * se2 + (size_t)m * ldc + q];
            } else if (MODE == 3) {
                val = 0.5f * val + 0.5f * e2[(size_t)n * se2 + (size_t)m * ldc + q];
            }
            crow[j] = val;
        }
    }
}

// ---------------- K5: in-place threshold + symmetrize B (r1 version) ----------------
__global__ void k_symB(float* __restrict__ B) {
    int p = blockIdx.x, n = blockIdx.y;
    float* Bb = B + (size_t)n * HW * HW;
    for (int q = p + threadIdx.x; q < HW; q += 256) {
        float x = Bb[(size_t)p * HW + q];
        float y = Bb[(size_t)q * HW + p];
        x = x < 0.15f ? 0.f : x;
        y = y < 0.15f ? 0.f : y;
        float m = 0.5f * (x + y);
        Bb[(size_t)p * HW + q] = m;
        Bb[(size_t)q * HW + p] = m;
    }
}

// ---------------- K6: rowsums for sim_c (rank-1) and sim_s (from Bsym) ----------------
__global__ void k_rowsum_cs(const float* __restrict__ B, const float* __restrict__ u,
                            const float* __restrict__ vv, float* __restrict__ dcinv,
                            float* __restrict__ dsinv) {
    int p = blockIdx.x, n = blockIdx.y, tid = threadIdx.x;
    const float* Bb = B + (size_t)n * HW * HW + (size_t)p * HW;
    const float* un = u + n * HW;
    const float* vn = vv + n * HW;
    float up = un[p], vp = vn[p];
    float acc_s = 0.f, acc_c = 0.f;
    for (int q = tid; q < HW; q += 256) {
        acc_s += Bb[q];
        float x = up * vn[q]; x = x < 0.15f ? 0.f : x;
        float y = un[q] * vp; y = y < 0.15f ? 0.f : y;
        acc_c += 0.5f * (x + y);
    }
    __shared__ float s4[4];
    acc_s = blockReduceSum(acc_s, s4);
    acc_c = blockReduceSum(acc_c, s4);
    if (tid == 0) {
        dsinv[n * HW + p] = 1.0f / sqrtf(acc_s + 1.0f);
        dcinv[n * HW + p] = 1.0f / sqrtf(acc_c + 1.0f);
    }
}

// ---------------- K7: sim_pre (in place over Bsym), rowsum -> dfinv ----------------
__global__ void k_build_sim(float* __restrict__ B, const float* __restrict__ u,
                            const float* __restrict__ vv, const float* __restrict__ dcinv,
                            const float* __restrict__ dsinv, float* __restrict__ dfinv) {
    int p = blockIdx.x, n = blockIdx.y, tid = threadIdx.x;
    float* Bb = B + (size_t)n * HW * HW + (size_t)p * HW;
    const float* un = u + n * HW;
    const float* vn = vv + n * HW;
    const float* dci = dcinv + n * HW;
    const float* dsi = dsinv + n * HW;
    float up = un[p], vp = vn[p], dcp = dci[p], dsp = dsi[p];
    float acc = 0.f;
    for (int q = tid; q < HW; q += 256) {
        float x = up * vn[q]; x = x < 0.15f ? 0.f : x;
        float y = un[q] * vp; y = y < 0.15f ? 0.f : y;
        float delta = (q == p) ? 1.0f : 0.0f;
        float val = (0.5f * (x + y) + delta) * dcp * dci[q] + (Bb[q] + delta) * dsp * dsi[q];
        Bb[q] = val;
        acc += val;
    }
    __shared__ float s4[4];
    acc = blockReduceSum(acc, s4);
    if (tid == 0) dfinv[n * HW + p] = 1.0f / sqrtf(acc + 1.0f);
}

// ---------------- K8: sim = (sim_pre + I)*dfinv_p*dfinv_q ; ACCUM (= or +=) ----------------
__global__ void k_norm_accum(float* __restrict__ B, const float* __restrict__ dfinv,
                             float* __restrict__ ACC, int first) {
    int p = blockIdx.x, n = blockIdx.y, tid = threadIdx.x;
    float* Bb = B + (size_t)n * HW * HW + (size_t)p * HW;
    float* Ab = ACC + (size_t)n * HW * HW + (size_t)p * HW;
    const float* df = dfinv + n * HW;
    float dfp = df[p];
    for (int q = tid; q < HW; q += 256) {
        float val = (Bb[q] + ((q == p) ? 1.f : 0.f)) * dfp * df[q];
        Bb[q] = val;
        Ab[q] = first ? val : (Ab[q] + val);
    }
}

// ---------------- K11: final rowsum of mean adjacency ----------------
__global__ void k_final_rowsum(const float* __restrict__ ACC, float* __restrict__ dinv) {
    int p = blockIdx.x, n = blockIdx.y, tid = threadIdx.x;
    const float* Ab = ACC + (size_t)n * HW * HW + (size_t)p * HW;
    float acc = 0.f;
    for (int q = tid; q < HW; q += 256) acc += Ab[q];
    __shared__ float s4[4];
    acc = blockReduceSum(acc, s4);
    if (tid == 0) dinv[n * HW + p] = 1.0f / sqrtf(acc * (1.0f / 3.0f) + 1.0f);
}

// ---------------- K12: final normalize (in place, f32) + PER-ROW stats (no global atomics) ----------------
__global__ void k_final_norm(float* __restrict__ ACC, const float* __restrict__ dinv,
                             float* __restrict__ rowsf, float* __restrict__ diagrow,
                             float* __restrict__ sqrow) {
    int p = blockIdx.x, n = blockIdx.y, tid = threadIdx.x;
    float* Ab = ACC + (size_t)n * HW * HW + (size_t)p * HW;
    const float* di = dinv + n * HW;
    float dp = di[p];
    float accr = 0.f, accsq = 0.f, accd = 0.f;
    for (int q = tid; q < HW; q += 256) {
        float val = (Ab[q] * (1.0f / 3.0f) + ((q == p) ? 1.f : 0.f)) * dp * di[q];
        Ab[q] = val;
        accr += val;
        accsq += val * val;
        if (q == p) accd = val;
    }
    __shared__ float s4[4];
    accr = blockReduceSum(accr, s4);
    accsq = blockReduceSum(accsq, s4);
    accd = blockReduceSum(accd, s4);
    if (tid == 0) {
        rowsf[n * HW + p] = accr;
        sqrow[n * HW + p] = accsq;
        diagrow[n * HW + p] = accd;
    }
}

// ---------------- K12b: global scalar reduce (trace, sumsq) ----------------
__global__ void k_scal(const float* __restrict__ diagrow, const float* __restrict__ sqrow,
                       float* __restrict__ scal) {
    int tid = threadIdx.x;
    float a = 0.f, b = 0.f;
    for (int i = tid; i < NB * HW; i += 256) { a += diagrow[i]; b += sqrow[i]; }
    __shared__ float s4[4];
    a = blockReduceSum(a, s4);
    b = blockReduceSum(b, s4);
    if (tid == 0) { scal[0] = a; scal[1] = b; }
}

// ---------------- K13: regularizer ----------------
__global__ void k_reg(const float* __restrict__ rowsf, const float* __restrict__ scal,
                      float* __restrict__ outreg) {
    int n = blockIdx.x, tid = threadIdx.x;
    float acc = 0.f;
    for (int p = tid; p < HW; p += 256) acc += logf(rowsf[n * HW + p]);
    __shared__ float s4[4];
    acc = blockReduceSum(acc, s4);
    if (tid == 0) {
        float f = -0.1f * acc / 1024.0f + 0.1f * sqrtf(scal[1]) / 1048576.0f;
        outreg[n] = 0.1f * scal[0] + f;
    }
}

// ---------------- K14: APPNP t ----------------
__global__ void k_appnp_t(const float* __restrict__ ori, const float* __restrict__ wa1,
                          const float* __restrict__ ba1, const float* __restrict__ wa2,
                          const float* __restrict__ ba2, float* __restrict__ T) {
    int p = blockIdx.x, n = blockIdx.y, tid = threadIdx.x;
    const float* x = ori + (size_t)n * C * HW + (size_t)p * C;
    float xv = x[tid];
    __shared__ float s4[4];
    __shared__ float h[3];
    float d0 = blockReduceSum(xv * wa1[0 * C + tid], s4);
    float d1 = blockReduceSum(xv * wa1[1 * C + tid], s4);
    float d2 = blockReduceSum(xv * wa1[2 * C + tid], s4);
    if (tid == 0) {
        h[0] = fmaxf(d0 + ba1[0], 0.f);
        h[1] = fmaxf(d1 + ba1[1], 0.f);
        h[2] = fmaxf(d2 + ba1[2], 0.f);
    }
    __syncthreads();
    float t = h[0] * wa2[tid * 3 + 0] + h[1] * wa2[tid * 3 + 1] + h[2] * wa2[tid * 3 + 2] + ba2[tid];
    T[(size_t)n * HW * C + (size_t)p * C + tid] = fmaxf(t, 0.f);
}

// =====================================================================================
extern "C" void kernel_launch(void* const* d_in, const int* in_sizes, int n_in,
                              void* d_out, int out_size, void* d_ws, size_t ws_size,
                              hipStream_t stream) {
    const float* seg_in = (const float*)d_in[0];
    const float* edge   = (const float*)d_in[1];
    const float* ws1    = (const float*)d_in[2];
    const float* bs1    = (const float*)d_in[3];
    const float* ws11   = (const float*)d_in[4];
    const float* bs11   = (const float*)d_in[5];
    const float* ws2    = (const float*)d_in[6];
    const float* bs2    = (const float*)d_in[7];
    const float* ws3    = (const float*)d_in[8];
    const float* bs3    = (const float*)d_in[9];
    const float* wmlp   = (const float*)d_in[10];
    const float* bmlp   = (const float*)d_in[11];
    const float* wgcn   = (const float*)d_in[12];
    const float* bgcn   = (const float*)d_in[13];
    const float* wa1    = (const float*)d_in[14];
    const float* ba1    = (const float*)d_in[15];
    const float* wa2    = (const float*)d_in[16];
    const float* ba2    = (const float*)d_in[17];

    float* out = (float*)d_out;
    float* w = (float*)d_ws;
    float* SEG_A   = w; w += (size_t)NB * C * HW;    // 2M
    float* SEG_SIM = w; w += (size_t)NB * C * HW;    // 2M
    float* SEGS    = w; w += (size_t)NB * NS * HW;   // 512K
    float* SEGC    = w; w += (size_t)NB * NS * HW;   // 512K
    float* TBUF    = w; w += (size_t)NB * HW * C;    // 2M
    float* OBUF    = w; w += (size_t)NB * HW * C;    // 2M
    float* BBUF    = w; w += (size_t)NB * HW * HW;   // 8M
    float* ACCUM   = w; w += (size_t)NB * HW * HW;   // 8M
    float* ubuf    = w; w += NB * HW;
    float* vbuf    = w; w += NB * HW;
    float* ssbuf   = w; w += NB * HW;
    float* embuf   = w; w += NB * HW;
    float* dcinv   = w; w += NB * HW;
    float* dsinv   = w; w += NB * HW;
    float* dfinv   = w; w += NB * HW;
    float* rowsf   = w; w += NB * HW;
    float* diagrow = w; w += NB * HW;
    float* sqrow   = w; w += NB * HW;
    float* pooled  = w; w += NB * C;
    float* cabuf   = w; w += NB * NS;
    float* scal    = w; w += 16;

    const long long sAdj = (long long)HW * HW;
    const long long sSeg = (long long)C * HW;
    const long long sSgs = (long long)NS * HW;

    for (int it = 0; it < 3; ++it) {
        const float* seg_src = (it == 0) ? seg_in : SEG_A;
        k_conv_sc<<<dim3(NS, NB), 256, 0, stream>>>(seg_src, ws1, bs1, ws11, bs11, SEGS, SEGC);
        k_pooled<<<dim3(C, NB), 256, 0, stream>>>(seg_src, pooled);
        k_ca<<<dim3(NB), 64, 0, stream>>>(pooled, wmlp, bmlp, cabuf);
        k_vecs<<<dim3(4, NB, 4), 256, 0, stream>>>(seg_src, edge, SEGS, cabuf,
                                                   ws2, bs2, ws3, bs3,
                                                   ubuf, vbuf, ssbuf, embuf);
        // B[p,q] = (sigma_T @ sigma) * em[p] * ss[q]
        k_gemm64<1><<<dim3(16, 16, NB), 256, 0, stream>>>(SEGC, sSgs, NS, SEGC, sSgs, HW,
                                                          BBUF, sAdj, HW, NS,
                                                          embuf, HW, ssbuf, HW);
        k_symB<<<dim3(HW, NB), 256, 0, stream>>>(BBUF);
        k_rowsum_cs<<<dim3(HW, NB), 256, 0, stream>>>(BBUF, ubuf, vbuf, dcinv, dsinv);
        k_build_sim<<<dim3(HW, NB), 256, 0, stream>>>(BBUF, ubuf, vbuf, dcinv, dsinv, dfinv);
        k_norm_accum<<<dim3(HW, NB), 256, 0, stream>>>(BBUF, dfinv, ACCUM, it == 0 ? 1 : 0);
        // seg_sim = seg2 @ sim   (M=256, N=1024, K=1024)
        k_gemm64<0><<<dim3(16, 4, NB), 256, 0, stream>>>(seg_src, sSeg, HW, BBUF, sAdj, HW,
                                                         SEG_SIM, sSeg, HW, HW,
                                                         nullptr, 0, nullptr, 0);
        // seg_new = relu(wgcn @ seg_sim + bgcn) + seg2  (M=256, N=1024, K=256)
        k_gemm64<2><<<dim3(16, 4, NB), 256, 0, stream>>>(wgcn, 0, C, SEG_SIM, sSeg, HW,
                                                         SEG_A, sSeg, HW, C,
                                                         bgcn, 0, seg_src, sSeg);
    }

    // final adjacency: mean of 3 sims -> adj_process(., 0)
    k_final_rowsum<<<dim3(HW, NB), 256, 0, stream>>>(ACCUM, dcinv);
    k_final_norm<<<dim3(HW, NB), 256, 0, stream>>>(ACCUM, dcinv, rowsf, diagrow, sqrow);
    k_scal<<<dim3(1), 256, 0, stream>>>(diagrow, sqrow, scal);
    k_reg<<<dim3(NB), 256, 0, stream>>>(rowsf, scal, out + (size_t)NB * C * HW);

    // APPNP (f32, adj = normalized ACCUM)
    k_appnp_t<<<dim3(HW, NB), 256, 0, stream>>>(seg_in, wa1, ba1, wa2, ba2, TBUF);
    k_gemm64<3><<<dim3(4, 16, NB), 256, 0, stream>>>(ACCUM, sAdj, HW, TBUF, (long long)HW * C, C,
                                                     out, (long long)HW * C, C, HW,
                                                     nullptr, 0, TBUF, (long long)HW * C);
    k_gemm64<3><<<dim3(4, 16, NB), 256, 0, stream>>>(ACCUM, sAdj, HW, out, (long long)HW * C, C,
                                                     OBUF, (long long)HW * C, C, HW,
                                                     nullptr, 0, TBUF, (long long)HW * C);
    k_gemm64<3><<<dim3(4, 16, NB), 256, 0, stream>>>(ACCUM, sAdj, HW, OBUF, (long long)HW * C, C,
                                                     out, (long long)HW * C, C, HW,
                                                     nullptr, 0, TBUF, (long long)HW * C);
}